// Round 1
// baseline (794.702 us; speedup 1.0000x reference)
//
#include <hip/hip_runtime.h>
#include <hip/hip_bf16.h>

#define TT 2048
#define BB 512
#define HH 32

// tanh(x) = sign(x) * (1 - 2/(exp(2|x|)+1)); safe for large |x| (exp->inf -> 2/inf=0 -> 1)
__device__ __forceinline__ float fast_tanh(float u) {
    float a = fabsf(u);
    float e = __expf(2.0f * a);
    float t = 1.0f - 2.0f / (e + 1.0f);
    return (u < 0.0f) ? -t : t;
}

// One step for this lane (lane = hidden index j within its row-group).
// hrow: LDS row of 32 floats holding previous h (written by previous step, in-wave ordered).
__device__ __forceinline__ float rnn_step(const float4 xt[8], const float wx[32],
                                          const float wh[32], float bj,
                                          float* hrow, int lane) {
    float u0 = 0.f, u1 = 0.f, u2 = 0.f, u3 = 0.f;
#pragma unroll
    for (int q = 0; q < 8; ++q) {
        u0 = fmaf(xt[q].x, wx[4*q+0], u0);
        u1 = fmaf(xt[q].y, wx[4*q+1], u1);
        u2 = fmaf(xt[q].z, wx[4*q+2], u2);
        u3 = fmaf(xt[q].w, wx[4*q+3], u3);
    }
    const float4* hp = (const float4*)hrow;
#pragma unroll
    for (int q = 0; q < 8; ++q) {
        float4 hv = hp[q];   // broadcast read: same address across the 32-lane group
        u0 = fmaf(hv.x, wh[4*q+0], u0);
        u1 = fmaf(hv.y, wh[4*q+1], u1);
        u2 = fmaf(hv.z, wh[4*q+2], u2);
        u3 = fmaf(hv.w, wh[4*q+3], u3);
    }
    float u = bj + ((u0 + u1) + (u2 + u3));
    float hn = fast_tanh(u);
    hrow[lane] = hn;         // in-wave DS ordering: all reads above complete first
    return hn;
}

__global__ __launch_bounds__(64) void rnn_seq_kernel(
        const int* __restrict__ x, const float* __restrict__ emb,
        const float* __restrict__ W_rnn, const float* __restrict__ b_rnn,
        const float* __restrict__ W_cls, const float* __restrict__ b_cls,
        float* __restrict__ out) {
    const int lane = threadIdx.x & 31;
    const int grp  = threadIdx.x >> 5;          // 0 or 1
    const int row  = blockIdx.x * 2 + grp;      // batch index

    __shared__ float hbuf[2][HH];

    // Load this lane's weight columns into registers (once).
    float wx[32], wh[32];
#pragma unroll
    for (int k = 0; k < 32; ++k) {
        wx[k] = W_rnn[k * HH + lane];
        wh[k] = W_rnn[(HH + k) * HH + lane];
    }
    const float bj = b_rnn[lane];

    hbuf[grp][lane] = 0.0f;                     // h0 = 0 (single wave: no barrier needed)
    float* hrow = &hbuf[grp][0];

    // Software pipeline: xcur = emb row for step t; i1 = index for step t+1.
    int i0 = x[0 * BB + row];
    int i1 = x[1 * BB + row];
    float4 xcur[8], xnxt[8];
    {
        const float4* ep = (const float4*)(emb + (size_t)i0 * HH);
#pragma unroll
        for (int q = 0; q < 8; ++q) xcur[q] = ep[q];
    }

    for (int t = 0; t < TT; t += 2) {
        // ---- step t: prefetch idx(t+2), gather emb for t+1, compute with xcur ----
        int i2 = x[min(t + 2, TT - 1) * BB + row];
        {
            const float4* ep = (const float4*)(emb + (size_t)i1 * HH);
#pragma unroll
            for (int q = 0; q < 8; ++q) xnxt[q] = ep[q];
        }
        rnn_step(xcur, wx, wh, bj, hrow, lane);

        // ---- step t+1: prefetch idx(t+3), gather emb for t+2, compute with xnxt ----
        i1 = x[min(t + 3, TT - 1) * BB + row];
        {
            const float4* ep = (const float4*)(emb + (size_t)i2 * HH);
#pragma unroll
            for (int q = 0; q < 8; ++q) xcur[q] = ep[q];
        }
        rnn_step(xnxt, wx, wh, bj, hrow, lane);
    }

    // Epilogue: y = h_final @ W_cls + b_cls   (N_CLASS = 5)
    if (lane < 5) {
        float acc = b_cls[lane];
#pragma unroll
        for (int k = 0; k < 32; ++k)
            acc = fmaf(hrow[k], W_cls[k * 5 + lane], acc);
        out[row * 5 + lane] = acc;
    }
}

extern "C" void kernel_launch(void* const* d_in, const int* in_sizes, int n_in,
                              void* d_out, int out_size, void* d_ws, size_t ws_size,
                              hipStream_t stream) {
    const int*   x     = (const int*)d_in[0];
    const float* emb   = (const float*)d_in[1];
    const float* W_rnn = (const float*)d_in[2];
    const float* b_rnn = (const float*)d_in[3];
    const float* W_cls = (const float*)d_in[4];
    const float* b_cls = (const float*)d_in[5];
    float* out = (float*)d_out;

    rnn_seq_kernel<<<BB / 2, 64, 0, stream>>>(x, emb, W_rnn, b_rnn, W_cls, b_cls, out);
}

// Round 2
// 585.193 us; speedup vs baseline: 1.3580x; 1.3580x over previous
//
#include <hip/hip_runtime.h>
#include <hip/hip_bf16.h>

#define TT 2048
#define BB 512
#define HH 32
#define NPAIR (TT * BB)
#define PSTRIDE (BB * HH)   // floats per t-slice of P = 16384

// tanh(x) = sign(x) * (1 - 2/(exp(2|x|)+1)); safe for large |x|
__device__ __forceinline__ float fast_tanh(float u) {
    float a = fabsf(u);
    float e = __expf(2.0f * a);
    float t = 1.0f - 2.0f / (e + 1.0f);
    return (u < 0.0f) ? -t : t;
}

__device__ __forceinline__ float bcast(float v, int srclane) {
    return __uint_as_float(__builtin_amdgcn_readlane(__float_as_uint(v), srclane));
}

// ---------------- Pass 1: P[t][row][j] = b[j] + emb[x[t,row]] @ Wx[:,j] ----------------
template <bool FP32>
__global__ __launch_bounds__(256) void precompute_kernel(
        const int* __restrict__ x, const float* __restrict__ emb,
        const float* __restrict__ W_rnn, const float* __restrict__ b_rnn,
        void* __restrict__ Pv) {
    float*          Pf = (float*)Pv;
    __hip_bfloat16* Ph = (__hip_bfloat16*)Pv;
    const int lane = threadIdx.x & 31;
    int g        = (blockIdx.x * blockDim.x + threadIdx.x) >> 5;
    const int ng = (gridDim.x * blockDim.x) >> 5;

    float wx[32];
#pragma unroll
    for (int k = 0; k < 32; ++k) wx[k] = W_rnn[k * HH + lane];
    const float bj = b_rnn[lane];

    for (int pair = g; pair < NPAIR; pair += ng) {
        const int idx = x[pair];
        const float4* ep = (const float4*)(emb + (size_t)idx * HH);
        float u0 = bj, u1 = 0.f, u2 = 0.f, u3 = 0.f;
#pragma unroll
        for (int q = 0; q < 8; ++q) {
            float4 e = ep[q];   // broadcast load: same addr across the 32-lane group
            u0 = fmaf(e.x, wx[4*q+0], u0);
            u1 = fmaf(e.y, wx[4*q+1], u1);
            u2 = fmaf(e.z, wx[4*q+2], u2);
            u3 = fmaf(e.w, wx[4*q+3], u3);
        }
        float u = (u0 + u1) + (u2 + u3);
        if (FP32) Pf[(size_t)pair * HH + lane] = u;
        else      Ph[(size_t)pair * HH + lane] = __float2bfloat16(u);
    }
}

// ---------------- Pass 2: sequential scan, one row per wave, readlane h-broadcast ------
template <bool FP32>
__global__ __launch_bounds__(64) void rnn_seq_fast(
        const void* __restrict__ Pv, const float* __restrict__ W_rnn,
        const float* __restrict__ W_cls, const float* __restrict__ b_cls,
        float* __restrict__ out) {
    const int j   = threadIdx.x & 31;   // both 32-lane halves duplicate the same row
    const int row = blockIdx.x;

    float wh[32];
#pragma unroll
    for (int k = 0; k < 32; ++k) wh[k] = W_rnn[(HH + k) * HH + j];

    const float*          Pf = (const float*)Pv;
    const __hip_bfloat16* Ph = (const __hip_bfloat16*)Pv;
    const size_t base = (size_t)row * HH + j;

    float h = 0.0f;
    float p[8];
#pragma unroll
    for (int d = 0; d < 8; ++d)
        p[d] = FP32 ? Pf[(size_t)d * PSTRIDE + base]
                    : __bfloat162float(Ph[(size_t)d * PSTRIDE + base]);

    for (int t = 0; t < TT; t += 8) {
#pragma unroll
        for (int d = 0; d < 8; ++d) {
            float u = p[d];
            // prefetch step t+d+8 into the freed slot (clamped; redundant loads harmless)
            int tn = t + d + 8;
            if (tn > TT - 1) tn = TT - 1;
            size_t off = (size_t)tn * PSTRIDE + base;
            p[d] = FP32 ? Pf[off] : __bfloat162float(Ph[off]);

            float u0 = u, u1 = 0.f, u2 = 0.f, u3 = 0.f;
#pragma unroll
            for (int q = 0; q < 8; ++q) {
                float h0 = bcast(h, 4*q+0);
                float h1 = bcast(h, 4*q+1);
                float h2 = bcast(h, 4*q+2);
                float h3 = bcast(h, 4*q+3);
                u0 = fmaf(h0, wh[4*q+0], u0);
                u1 = fmaf(h1, wh[4*q+1], u1);
                u2 = fmaf(h2, wh[4*q+2], u2);
                u3 = fmaf(h3, wh[4*q+3], u3);
            }
            h = fast_tanh((u0 + u1) + (u2 + u3));
        }
    }

    if (threadIdx.x < 5) {   // epilogue: y = h @ W_cls + b_cls
        float acc = b_cls[j];
#pragma unroll
        for (int k = 0; k < 32; ++k)
            acc = fmaf(bcast(h, k), W_cls[k * 5 + j], acc);
        out[row * 5 + j] = acc;
    }
}

// ---------------- Fallback (R1 kernel): fused, for tiny workspace ----------------------
__device__ __forceinline__ float rnn_step(const float4 xt[8], const float wx[32],
                                          const float wh[32], float bj,
                                          float* hrow, int lane) {
    float u0 = 0.f, u1 = 0.f, u2 = 0.f, u3 = 0.f;
#pragma unroll
    for (int q = 0; q < 8; ++q) {
        u0 = fmaf(xt[q].x, wx[4*q+0], u0);
        u1 = fmaf(xt[q].y, wx[4*q+1], u1);
        u2 = fmaf(xt[q].z, wx[4*q+2], u2);
        u3 = fmaf(xt[q].w, wx[4*q+3], u3);
    }
    const float4* hp = (const float4*)hrow;
#pragma unroll
    for (int q = 0; q < 8; ++q) {
        float4 hv = hp[q];
        u0 = fmaf(hv.x, wh[4*q+0], u0);
        u1 = fmaf(hv.y, wh[4*q+1], u1);
        u2 = fmaf(hv.z, wh[4*q+2], u2);
        u3 = fmaf(hv.w, wh[4*q+3], u3);
    }
    float hn = fast_tanh(bj + ((u0 + u1) + (u2 + u3)));
    hrow[lane] = hn;
    return hn;
}

__global__ __launch_bounds__(64) void rnn_seq_kernel(
        const int* __restrict__ x, const float* __restrict__ emb,
        const float* __restrict__ W_rnn, const float* __restrict__ b_rnn,
        const float* __restrict__ W_cls, const float* __restrict__ b_cls,
        float* __restrict__ out) {
    const int lane = threadIdx.x & 31;
    const int grp  = threadIdx.x >> 5;
    const int row  = blockIdx.x * 2 + grp;
    __shared__ float hbuf[2][HH];
    float wx[32], wh[32];
#pragma unroll
    for (int k = 0; k < 32; ++k) {
        wx[k] = W_rnn[k * HH + lane];
        wh[k] = W_rnn[(HH + k) * HH + lane];
    }
    const float bj = b_rnn[lane];
    hbuf[grp][lane] = 0.0f;
    float* hrow = &hbuf[grp][0];
    int i0 = x[0 * BB + row];
    int i1 = x[1 * BB + row];
    float4 xcur[8], xnxt[8];
    {
        const float4* ep = (const float4*)(emb + (size_t)i0 * HH);
#pragma unroll
        for (int q = 0; q < 8; ++q) xcur[q] = ep[q];
    }
    for (int t = 0; t < TT; t += 2) {
        int i2 = x[min(t + 2, TT - 1) * BB + row];
        {
            const float4* ep = (const float4*)(emb + (size_t)i1 * HH);
#pragma unroll
            for (int q = 0; q < 8; ++q) xnxt[q] = ep[q];
        }
        rnn_step(xcur, wx, wh, bj, hrow, lane);
        i1 = x[min(t + 3, TT - 1) * BB + row];
        {
            const float4* ep = (const float4*)(emb + (size_t)i2 * HH);
#pragma unroll
            for (int q = 0; q < 8; ++q) xcur[q] = ep[q];
        }
        rnn_step(xnxt, wx, wh, bj, hrow, lane);
    }
    if (lane < 5) {
        float acc = b_cls[lane];
#pragma unroll
        for (int k = 0; k < 32; ++k)
            acc = fmaf(hrow[k], W_cls[k * 5 + lane], acc);
        out[row * 5 + lane] = acc;
    }
}

extern "C" void kernel_launch(void* const* d_in, const int* in_sizes, int n_in,
                              void* d_out, int out_size, void* d_ws, size_t ws_size,
                              hipStream_t stream) {
    const int*   x     = (const int*)d_in[0];
    const float* emb   = (const float*)d_in[1];
    const float* W_rnn = (const float*)d_in[2];
    const float* b_rnn = (const float*)d_in[3];
    const float* W_cls = (const float*)d_in[4];
    const float* b_cls = (const float*)d_in[5];
    float* out = (float*)d_out;

    const size_t need32 = (size_t)NPAIR * HH * 4;   // 128 MiB
    const size_t need16 = (size_t)NPAIR * HH * 2;   //  64 MiB

    if (ws_size >= need32) {
        precompute_kernel<true><<<2048, 256, 0, stream>>>(x, emb, W_rnn, b_rnn, d_ws);
        rnn_seq_fast<true><<<BB, 64, 0, stream>>>(d_ws, W_rnn, W_cls, b_cls, out);
    } else if (ws_size >= need16) {
        precompute_kernel<false><<<2048, 256, 0, stream>>>(x, emb, W_rnn, b_rnn, d_ws);
        rnn_seq_fast<false><<<BB, 64, 0, stream>>>(d_ws, W_rnn, W_cls, b_cls, out);
    } else {
        rnn_seq_kernel<<<BB / 2, 64, 0, stream>>>(x, emb, W_rnn, b_rnn, W_cls, b_cls, out);
    }
}